// Round 6
// baseline (57.485 us; speedup 1.0000x reference)
//
#include <hip/hip_runtime.h>

// 1-D hash-grid embedder, 8 levels, 2 feats, fp32, B = 4.19M.
//
// Round-5 post-mortem: 57.3us vs ~40us pure-store floor. Fill kernels need
// ~3 waves/CU (no deps); our x-load -> LDS-gather -> store chain at only
// 16 waves/CU (65KB LDS capped 2 blocks/CU) can't fully cover HBM+LDS latency.
//
// This version: compact float2 staging (4088 entries = 32.7KB). Gather is
// 4x ds_read_b64 (same LDS-pipe cycles as 2x b128) but LDS halves ->
// 4 blocks/CU = 32 waves/CU (grid 1024). off(l) = 16*(2^l-1) + l computed
// arithmetically; unroll 2 to keep VGPR <= 64 for 8 waves/EU.
//
// Numerics: res = 16<<l power of two, fx = x*res exact,
// w = fx - floor(fx) bit-identical to reference (x - idx*gs)/gs.

#define NGP_BATCH   4194304
#define NGP_TSIZE   (1 << 19)
#define BLOCK       512
#define PPB         4096                // points per block
#define KITER       (PPB / (BLOCK/4))   // 32 iterations of 128 points

typedef float f32x4 __attribute__((ext_vector_type(4)));

__global__ __launch_bounds__(BLOCK, 8) void hashenc_kernel(
    const float* __restrict__ x,
    const float* __restrict__ tables,
    float* __restrict__ out)
{
    // level l at off(l) = 16*((1<<l)-1) + l, size (16<<l)+1 float2 entries
    __shared__ float2 sm[4088];   // 32704 B -> 4 blocks/CU, 32 waves/CU

    const int tid = threadIdx.x;

    // ---- stage compact hot region: level l entries 0..(16<<l) ----
#pragma unroll
    for (int l = 0; l < 8; ++l) {
        const int n   = (16 << l) + 1;
        const int off = 16 * ((1 << l) - 1) + l;
        const float2* __restrict__ src =
            reinterpret_cast<const float2*>(tables) + (size_t)l * NGP_TSIZE;
        for (int e = tid; e < n; e += BLOCK)
            sm[off + e] = src[e];
    }
    __syncthreads();

    const int q  = tid >> 2;
    const int s  = tid & 3;
    const int l0 = 2 * s;
    const int l1 = 2 * s + 1;
    const float res0 = (float)(16 << l0);
    const float res1 = (float)(16 << l1);
    const int   off0 = 16 * ((1 << l0) - 1) + l0;
    const int   off1 = 16 * ((1 << l1) - 1) + l1;

    const int P0 = blockIdx.x * PPB;
    f32x4* __restrict__ out4 = reinterpret_cast<f32x4*>(out);

#pragma unroll 2
    for (int k = 0; k < KITER; ++k) {
        const int   p  = P0 + q + 128 * k;
        const float xv = x[p];

        const float fx0 = xv * res0;             // exact pow2 scale
        const float fi0 = floorf(fx0);
        const float w0  = fx0 - fi0;             // == reference w
        const int   i0  = off0 + (int)fi0;
        const float2 a0 = sm[i0];
        const float2 b0 = sm[i0 + 1];

        const float fx1 = xv * res1;
        const float fi1 = floorf(fx1);
        const float w1  = fx1 - fi1;
        const int   i1  = off1 + (int)fi1;
        const float2 a1 = sm[i1];
        const float2 b1 = sm[i1 + 1];

        f32x4 r;
        r.x = a0.x * (1.0f - w0) + b0.x * w0;
        r.y = a0.y * (1.0f - w0) + b0.y * w0;
        r.z = a1.x * (1.0f - w1) + b1.x * w1;
        r.w = a1.y * (1.0f - w1) + b1.y * w1;

        __builtin_nontemporal_store(r, &out4[(size_t)p * 4 + s]);  // 1KB/wave burst
    }
}

extern "C" void kernel_launch(void* const* d_in, const int* in_sizes, int n_in,
                              void* d_out, int out_size, void* d_ws, size_t ws_size,
                              hipStream_t stream) {
    const float* x      = (const float*)d_in[0];
    const float* tables = (const float*)d_in[1];
    float*       out    = (float*)d_out;

    const int grid = NGP_BATCH / PPB;   // 1024 blocks = 4 per CU resident
    hashenc_kernel<<<grid, BLOCK, 0, stream>>>(x, tables, out);
}